// Round 2
// baseline (959.404 us; speedup 1.0000x reference)
//
#include <hip/hip_runtime.h>
#include <hip/hip_bf16.h>
#include <math.h>

using bf16 = __hip_bfloat16;

#define H_IMG 128
#define W_IMG 128
#define C_IN  200
#define NCLS  16
#define N0    16384
#define N1    4096
#define N2    1024
#define KNB   16
#define EPS   1e-5f
#define SLOPE 0.01f

__device__ __forceinline__ float ldf(const float* p, long i) { return p[i]; }
__device__ __forceinline__ float ldf(const bf16* p, long i) { return __bfloat162float(p[i]); }
__device__ __forceinline__ float leaky(float v) { return v >= 0.f ? v : SLOPE * v; }

__device__ __forceinline__ float4 ld4(const float* p, long i) {
    return *reinterpret_cast<const float4*>(p + i);
}
__device__ __forceinline__ float4 ld4(const bf16* p, long i) {
    const ushort4 u = *reinterpret_cast<const ushort4*>(reinterpret_cast<const unsigned short*>(p) + i);
    float4 r;
    r.x = __uint_as_float((unsigned)u.x << 16);
    r.y = __uint_as_float((unsigned)u.y << 16);
    r.z = __uint_as_float((unsigned)u.z << 16);
    r.w = __uint_as_float((unsigned)u.w << 16);
    return r;
}

// ---------- per-block dtype detection (fp32 read as bf16 stream shows wild exponents) ----------
__device__ __forceinline__ int block_detect(const unsigned short* __restrict__ x) {
    __shared__ int cnt_s;
    if (threadIdx.x == 0) cnt_s = 0;
    __syncthreads();
    int cnt = 0;
    for (int i = threadIdx.x; i < 4096; i += blockDim.x) {
        unsigned short e = (unsigned short)((x[i] >> 7) & 0xFF);
        if (e >= 0xC0) cnt++;
    }
#pragma unroll
    for (int off = 32; off > 0; off >>= 1) cnt += __shfl_xor(cnt, off, 64);
    if ((threadIdx.x & 63) == 0) atomicAdd(&cnt_s, cnt);
    __syncthreads();
    return cnt_s > 32 ? 1 : 0;
}

// ---------------- BN stage A on raw input x (embedded detect; writes dflag from block 0) ----------------
__global__ __launch_bounds__(256) void bnx_kernel(const void* __restrict__ X, float2* __restrict__ part,
                                                  int* __restrict__ dflag) {
    int fl = block_detect((const unsigned short*)X);
    if (blockIdx.x == 0 && threadIdx.x == 0) *dflag = fl;
    int b = blockIdx.x, t = threadIdx.x;
    if (t >= C_IN) return;
    float s = 0.f, s2 = 0.f;
    if (fl) {
        const float* p = (const float*)X + (long)b * 64 * C_IN + t;
        for (int r = 0; r < 64; r++) { float v = p[(long)r * C_IN]; s += v; s2 += v * v; }
    } else {
        const bf16* p = (const bf16*)X + (long)b * 64 * C_IN + t;
        for (int r = 0; r < 64; r++) { float v = __bfloat162float(p[(long)r * C_IN]); s += v; s2 += v * v; }
    }
    part[(long)t * 256 + b] = make_float2(s, s2);
}

// ---------------- alpha/beta from partials (into LDS), then fold ----------------
__device__ __forceinline__ void alphabeta_ld(const float2* __restrict__ partA, int npA, int splitC,
                                             const float2* __restrict__ partB, int npB,
                                             int Ci, float Pinv, const void* g, const void* b_,
                                             int flag, float* al, float* be) {
    int t = threadIdx.x;
    if (t < Ci) {
        const float2* src = (t < splitC) ? partA + (long)t * npA : partB + (long)(t - splitC) * npB;
        int np = (t < splitC) ? npA : npB;
        float s = 0.f, s2 = 0.f;
        const float4* p4 = (const float4*)src;
        for (int i = 0; i < (np >> 1); i++) { float4 v = p4[i]; s += v.x + v.z; s2 += v.y + v.w; }
        float mu = s * Pinv;
        float var = s2 * Pinv - mu * mu;
        float gv = flag ? ((const float*)g)[t] : __bfloat162float(((const bf16*)g)[t]);
        float bv = flag ? ((const float*)b_)[t] : __bfloat162float(((const bf16*)b_)[t]);
        float a = rsqrtf(var + EPS) * gv;
        al[t] = a;
        be[t] = bv - mu * a;
    }
    __syncthreads();
}

template <typename TW>
__device__ __forceinline__ void foldL_body(const TW* __restrict__ W, const TW* __restrict__ bias,
                                           const float* __restrict__ al, const float* __restrict__ be,
                                           float* __restrict__ Wf, float* __restrict__ Bf,
                                           int Ci, int Co, int omajor, int j) {
    int t = threadIdx.x;
    float acc = 0.f;
    for (int c = t; c < Ci; c += 256) {
        float w = omajor ? ldf(W, (long)j * Ci + c) : ldf(W, (long)c * Co + j);
        Wf[(long)c * Co + j] = w * al[c];
        acc += w * be[c];
    }
    __shared__ float red[256];
    red[t] = acc; __syncthreads();
    for (int k = 128; k > 0; k >>= 1) { if (t < k) red[t] += red[t + k]; __syncthreads(); }
    if (t == 0) Bf[j] = ldf(bias, (long)j) + red[0];
}

// fused BN-reduce + fold (one matrix)
__global__ __launch_bounds__(256) void bnfold_kernel(const float2* partA, int npA, int splitC,
                                                     const float2* partB, int npB, int P,
                                                     const void* g, const void* b_,
                                                     const void* Wt, const void* bias,
                                                     float* Wf, float* Bf, int Ci, int Co, int omajor,
                                                     const int* dflag) {
    __shared__ float al[256], be[256];
    int flag = *dflag;
    alphabeta_ld(partA, npA, splitC, partB, npB, Ci, 1.f / (float)P, g, b_, flag, al, be);
    if (flag) foldL_body<float>((const float*)Wt, (const float*)bias, al, be, Wf, Bf, Ci, Co, omajor, blockIdx.x);
    else foldL_body<bf16>((const bf16*)Wt, (const bf16*)bias, al, be, Wf, Bf, Ci, Co, omajor, blockIdx.x);
}

// fused BN-reduce + fold (two matrices sharing alpha/beta, both c-major)
__global__ __launch_bounds__(256) void bnfold2_kernel(const float2* partA, int npA, int splitC,
                                                      const float2* partB, int npB, int P,
                                                      const void* g, const void* b_,
                                                      const void* W1, const void* b1,
                                                      const void* W2, const void* b2,
                                                      float* Wf1, float* Bf1, float* Wf2, float* Bf2,
                                                      int Ci, int Co1, int Co2, const int* dflag) {
    __shared__ float al[256], be[256];
    int flag = *dflag;
    alphabeta_ld(partA, npA, splitC, partB, npB, Ci, 1.f / (float)P, g, b_, flag, al, be);
    int j = blockIdx.x;
    if (flag) {
        if (j < Co1) foldL_body<float>((const float*)W1, (const float*)b1, al, be, Wf1, Bf1, Ci, Co1, 0, j);
        else foldL_body<float>((const float*)W2, (const float*)b2, al, be, Wf2, Bf2, Ci, Co2, 0, j - Co1);
    } else {
        if (j < Co1) foldL_body<bf16>((const bf16*)W1, (const bf16*)b1, al, be, Wf1, Bf1, Ci, Co1, 0, j);
        else foldL_body<bf16>((const bf16*)W2, (const bf16*)b2, al, be, Wf2, Bf2, Ci, Co2, 0, j - Co1);
    }
}

// ---------------- GEMM cores ----------------
template <typename T, int ACT>
__device__ __forceinline__ void gemm4_body(const T* __restrict__ In, const float* __restrict__ Wf,
                                           const float* __restrict__ Bf, float* __restrict__ Out,
                                           int Ci, int Co, int blk) {
    int tid = blk * 256 + threadIdx.x;
    int Coq = Co >> 2;
    int n = tid / Coq;
    int j4 = (tid - n * Coq) << 2;
    const T* in = In + (long)n * Ci;
    const float* wp = Wf + j4;
    float4 acc = *reinterpret_cast<const float4*>(Bf + j4);
    for (int c = 0; c < Ci; c += 4) {
        float4 xv = ld4(in, c);
        float4 w0 = *reinterpret_cast<const float4*>(wp + (long)c * Co);
        float4 w1 = *reinterpret_cast<const float4*>(wp + (long)(c + 1) * Co);
        float4 w2 = *reinterpret_cast<const float4*>(wp + (long)(c + 2) * Co);
        float4 w3 = *reinterpret_cast<const float4*>(wp + (long)(c + 3) * Co);
        acc.x += xv.x * w0.x; acc.y += xv.x * w0.y; acc.z += xv.x * w0.z; acc.w += xv.x * w0.w;
        acc.x += xv.y * w1.x; acc.y += xv.y * w1.y; acc.z += xv.y * w1.z; acc.w += xv.y * w1.w;
        acc.x += xv.z * w2.x; acc.y += xv.z * w2.y; acc.z += xv.z * w2.z; acc.w += xv.z * w2.w;
        acc.x += xv.w * w3.x; acc.y += xv.w * w3.y; acc.z += xv.w * w3.z; acc.w += xv.w * w3.w;
    }
    if (ACT) { acc.x = leaky(acc.x); acc.y = leaky(acc.y); acc.z = leaky(acc.z); acc.w = leaky(acc.w); }
    *reinterpret_cast<float4*>(Out + (long)n * Co + j4) = acc;
}

// dual-source (virtual concat) variant: c<SPLIT from InA (row n>>2), else InB (row n)
template <int ACT, int SPLIT>
__device__ __forceinline__ void gemm4cat_body(const float* __restrict__ InA, int sA,
                                              const float* __restrict__ InB, int sB,
                                              const float* __restrict__ Wf, const float* __restrict__ Bf,
                                              float* __restrict__ Out, int Ci, int Co, int blk) {
    int tid = blk * 256 + threadIdx.x;
    int Coq = Co >> 2;
    int n = tid / Coq;
    int j4 = (tid - n * Coq) << 2;
    const float* ia = InA + (long)(n >> 2) * sA;
    const float* ib = InB + (long)n * sB;
    const float* wp = Wf + j4;
    float4 acc = *reinterpret_cast<const float4*>(Bf + j4);
    for (int c = 0; c < Ci; c += 4) {
        float4 xv = (c < SPLIT) ? *reinterpret_cast<const float4*>(ia + c)
                                : *reinterpret_cast<const float4*>(ib + (c - SPLIT));
        float4 w0 = *reinterpret_cast<const float4*>(wp + (long)c * Co);
        float4 w1 = *reinterpret_cast<const float4*>(wp + (long)(c + 1) * Co);
        float4 w2 = *reinterpret_cast<const float4*>(wp + (long)(c + 2) * Co);
        float4 w3 = *reinterpret_cast<const float4*>(wp + (long)(c + 3) * Co);
        acc.x += xv.x * w0.x; acc.y += xv.x * w0.y; acc.z += xv.x * w0.z; acc.w += xv.x * w0.w;
        acc.x += xv.y * w1.x; acc.y += xv.y * w1.y; acc.z += xv.y * w1.z; acc.w += xv.y * w1.w;
        acc.x += xv.z * w2.x; acc.y += xv.z * w2.y; acc.z += xv.z * w2.z; acc.w += xv.z * w2.w;
        acc.x += xv.w * w3.x; acc.y += xv.w * w3.y; acc.z += xv.w * w3.z; acc.w += xv.w * w3.w;
    }
    if (ACT) { acc.x = leaky(acc.x); acc.y = leaky(acc.y); acc.z = leaky(acc.z); acc.w = leaky(acc.w); }
    *reinterpret_cast<float4*>(Out + (long)n * Co + j4) = acc;
}

__global__ __launch_bounds__(256) void gemm4_dyn_kernel(const void* In, const float* Wf, const float* Bf,
                                                        float* Out, int Ci, int Co, const int* flag) {
    if (*flag) gemm4_body<float, 1>((const float*)In, Wf, Bf, Out, Ci, Co, blockIdx.x);
    else gemm4_body<bf16, 1>((const bf16*)In, Wf, Bf, Out, Ci, Co, blockIdx.x);
}

// fused pair of GEMMs sharing plain input
__global__ __launch_bounds__(256) void gemm2_f32_kernel(const float* In,
                                                        const float* W1, const float* B1, float* O1, int Co1,
                                                        const float* W2, const float* B2, float* O2, int Co2,
                                                        int Ci, int nb1) {
    int b = blockIdx.x;
    if (b < nb1) gemm4_body<float, 0>(In, W1, B1, O1, Ci, Co1, b);
    else gemm4_body<float, 0>(In, W2, B2, O2, Ci, Co2, b - nb1);
}

// fused pair of GEMMs on virtual-concat input (d0)
template <int SPLIT>
__global__ __launch_bounds__(256) void gemm2cat_kernel(const float* InA, int sA, const float* InB, int sB,
                                                       const float* W1, const float* B1, float* O1, int Co1,
                                                       const float* W2, const float* B2, float* O2, int Co2,
                                                       int Ci, int nb1) {
    int b = blockIdx.x;
    if (b < nb1) gemm4cat_body<0, SPLIT>(InA, sA, InB, sB, W1, B1, O1, Ci, Co1, b);
    else gemm4cat_body<0, SPLIT>(InA, sA, InB, sB, W2, B2, O2, Ci, Co2, b - nb1);
}

// single GEMM on virtual-concat input with activation (tail)
template <int SPLIT>
__global__ __launch_bounds__(256) void gemmcat_act_kernel(const float* InA, int sA, const float* InB, int sB,
                                                          const float* Wf, const float* Bf, float* Out,
                                                          int Ci, int Co) {
    gemm4cat_body<1, SPLIT>(InA, sA, InB, sB, Wf, Bf, Out, Ci, Co, blockIdx.x);
}

// ---------------- depthwise 5x5 SAME + bias + leaky (4 ch/thread, weights in LDS) ----------------
template <typename TW>
__device__ __forceinline__ void dw4_body(const float* __restrict__ In, const TW* __restrict__ dwp,
                                         const TW* __restrict__ dbp, float* __restrict__ Out) {
    __shared__ float wl[25][128];
    __shared__ float bl[128];
    int t = threadIdx.x;
    for (int e = t; e < 25 * 128; e += 256) {
        int o = e / 25, i = e - o * 25;
        wl[i][o] = ldf(dwp, e);
    }
    if (t < 128) bl[t] = ldf(dbp, (long)t);
    __syncthreads();

    int tid = blockIdx.x * 256 + t;
    int o0 = (tid & 31) << 2;
    int p = tid >> 5;
    int h = p >> 7, w = p & 127;
    float4 acc = *reinterpret_cast<const float4*>(&bl[o0]);
#pragma unroll
    for (int dh = -2; dh <= 2; dh++) {
        int hh = h + dh;
        if ((unsigned)hh >= (unsigned)H_IMG) continue;
#pragma unroll
        for (int dv = -2; dv <= 2; dv++) {
            int ww = w + dv;
            if ((unsigned)ww >= (unsigned)W_IMG) continue;
            float4 iv = *reinterpret_cast<const float4*>(&In[(long)(((hh << 7) + ww) << 7) + o0]);
            float4 wv = *reinterpret_cast<const float4*>(&wl[(dh + 2) * 5 + (dv + 2)][o0]);
            acc.x += iv.x * wv.x; acc.y += iv.y * wv.y; acc.z += iv.z * wv.z; acc.w += iv.w * wv.w;
        }
    }
    acc.x = leaky(acc.x); acc.y = leaky(acc.y); acc.z = leaky(acc.z); acc.w = leaky(acc.w);
    *reinterpret_cast<float4*>(&Out[(long)p * 128 + o0]) = acc;
}

__global__ __launch_bounds__(256) void dw4_kernel(const float* In, const void* dwp, const void* dbp,
                                                  float* Out, const int* flag) {
    if (*flag) dw4_body<float>(In, (const float*)dwp, (const float*)dbp, Out);
    else dw4_body<bf16>(In, (const bf16*)dwp, (const bf16*)dbp, Out);
}

// ---------------- fused pool4 + BN-stageA over pooled rows + raw-R1 stats for tail BN ----------------
__global__ __launch_bounds__(128) void bnpool_kernel(const float* __restrict__ R1f, float* __restrict__ H1b,
                                                     float2* __restrict__ partE0, float2* __restrict__ partTb) {
    int b = blockIdx.x, t = threadIdx.x;   // 256 blocks x 128 threads; 16 pooled rows/block
    float s = 0.f, s2 = 0.f;               // pooled stats (e0 BN)
    float rs = 0.f, rs2 = 0.f;             // raw stats (tail BN, enc0 channels)
    const float* base = R1f + (long)b * 64 * 128 + t;
    for (int r = 0; r < 16; r++) {
        const float* rp = base + (long)r * 512;
        float v0 = rp[0], v1 = rp[128], v2 = rp[256], v3 = rp[384];
        float h = 0.25f * (v0 + v1 + v2 + v3);
        H1b[(long)(b * 16 + r) * 128 + t] = h;
        s += h; s2 += h * h;
        rs += v0 + v1 + v2 + v3;
        rs2 += v0 * v0 + v1 * v1 + v2 * v2 + v3 * v3;
    }
    partE0[(long)t * 256 + b] = make_float2(s, s2);
    partTb[(long)t * 256 + b] = make_float2(rs, rs2);
}

// ---------------- GCN attention (4 rows/block) + fused pool/stat emission ----------------
// MODE 0 (e0): writes dst(co=64), H2b = pool4(dst), partP = stats(H2b) np=snp, partS = stats(dst rows) np=snp
// MODE 1 (e1): writes dst(co=32), partS = 4x-weighted stats(dst rows) np=snp
// MODE 2 (d0): writes dst(co=64), partS = 4x-weighted stats(dst rows) np=snp
template <int MODE>
__global__ __launch_bounds__(256) void attn_fused_kernel(const float* __restrict__ th, const float* __restrict__ outm,
                                                         const int* __restrict__ nbr, float* __restrict__ dst, int co,
                                                         float* __restrict__ H2b,
                                                         float2* __restrict__ partP, float2* __restrict__ partS,
                                                         int snp) {
    int wid = threadIdx.x >> 6, l = threadIdx.x & 63;
    int n = blockIdx.x * 4 + wid;
    float r0 = th[(long)n * 128 + l];
    float r1 = th[(long)n * 128 + 64 + l];
    int mk[KNB];
    float av[KNB];
#pragma unroll
    for (int k = 0; k < KNB; k++) {
        int m = nbr[n * KNB + k];
        mk[k] = m;
        float v = r0 * th[(long)m * 128 + l] + r1 * th[(long)m * 128 + 64 + l];
#pragma unroll
        for (int off = 32; off > 0; off >>= 1) v += __shfl_xor(v, off, 64);
        av[k] = 1.f / (1.f + expf(-v));
    }
    float amax = av[0];
#pragma unroll
    for (int k = 1; k < KNB; k++) amax = fmaxf(amax, av[k]);
    float den = 0.f;
#pragma unroll
    for (int k = 0; k < KNB; k++) { av[k] = expf(av[k] - amax); den += av[k]; }
    float rden = 1.f / den;
    float val = 0.f;
    if (l < co) {
        float acc = 0.f;
#pragma unroll
        for (int k = 0; k < KNB; k++) acc += av[k] * outm[(long)mk[k] * co + l];
        val = leaky(acc * rden);
        dst[(long)n * co + l] = val;
    }
    __shared__ float sm[4][64];
    sm[wid][l] = (l < co) ? val : 0.f;
    __syncthreads();
    if (wid == 0 && l < co) {
        float a = sm[0][l], b = sm[1][l], c = sm[2][l], d = sm[3][l];
        float su = a + b + c + d;
        float sq = a * a + b * b + c * c + d * d;
        if (MODE == 0) {
            float h = 0.25f * su;
            H2b[(long)blockIdx.x * 64 + l] = h;
            partP[(long)l * snp + blockIdx.x] = make_float2(h, h * h);
            partS[(long)l * snp + blockIdx.x] = make_float2(su, sq);
        } else {
            partS[(long)l * snp + blockIdx.x] = make_float2(4.f * su, 4.f * sq);
        }
    }
}

// ---------------- classifier ----------------
template <typename TW>
__device__ __forceinline__ void cls_body(const float* __restrict__ F, const TW* __restrict__ wsw,
                                         const TW* __restrict__ wb, TW* __restrict__ out) {
    __shared__ float wl[128 * 16];
    int t = threadIdx.x;
    for (int e = t; e < 2048; e += 256) wl[e] = ldf(wsw, (long)e);
    __syncthreads();
    int tid = blockIdx.x * 256 + t;
    int p = tid >> 4;
    int j = tid & 15;
    float acc = ldf(wb, (long)j);
    const float* fp = F + (long)p * 128;
#pragma unroll 8
    for (int c = 0; c < 128; c += 4) {
        float4 fv = *reinterpret_cast<const float4*>(fp + c);
        acc += fv.x * wl[c * 16 + j] + fv.y * wl[(c + 1) * 16 + j]
             + fv.z * wl[(c + 2) * 16 + j] + fv.w * wl[(c + 3) * 16 + j];
    }
    float m = acc;
#pragma unroll
    for (int s = 8; s > 0; s >>= 1) m = fmaxf(m, __shfl_xor(m, s, 16));
    float e = expf(acc - m);
    float d = e;
#pragma unroll
    for (int s = 8; s > 0; s >>= 1) d += __shfl_xor(d, s, 16);
    float r = e / d;
    if constexpr (sizeof(TW) == 2) out[tid] = __float2bfloat16(r);
    else out[tid] = r;
}

__global__ __launch_bounds__(256) void cls_kernel(const float* F, const void* wsw, const void* wb,
                                                  void* out, const int* flag) {
    if (*flag) cls_body<float>(F, (const float*)wsw, (const float*)wb, (float*)out);
    else cls_body<bf16>(F, (const bf16*)wsw, (const bf16*)wb, (bf16*)out);
}

// ================= host side =================
extern "C" void kernel_launch(void* const* d_in, const int* in_sizes, int n_in,
                              void* d_out, int out_size, void* d_ws, size_t ws_size,
                              hipStream_t stream) {
    bool dict = (in_sizes[1] > 1000000);
    int I_x, I_nbr_a, I_nbr_b, I_hg, I_ws, I_e0, I_e1, I_d0, I_tg;
    if (dict) {
        I_x = 0; I_nbr_a = 5; I_nbr_b = 6; I_hg = 7; I_e0 = 13; I_e1 = 19; I_d0 = 25; I_tg = 31; I_ws = 37;
    } else {
        I_x = 0; I_hg = 1; I_e0 = 7; I_e1 = 13; I_d0 = 19; I_tg = 25; I_ws = 31; I_nbr_a = 37; I_nbr_b = 38;
    }
    const void* x    = d_in[I_x];
    const int* nbr_a = (const int*)d_in[I_nbr_a];
    const int* nbr_b = (const int*)d_in[I_nbr_b];
    const void* hg   = d_in[I_hg + 0];
    const void* hb   = d_in[I_hg + 1];
    const void* hpw  = d_in[I_hg + 2];
    const void* hpb  = d_in[I_hg + 3];
    const void* hdw  = d_in[I_hg + 4];
    const void* hdb  = d_in[I_hg + 5];
    const void* e0_g = d_in[I_e0 + 0];
    const void* e0_b = d_in[I_e0 + 1];
    const void* e0_wt= d_in[I_e0 + 2];
    const void* e0_bt= d_in[I_e0 + 3];
    const void* e0_wo= d_in[I_e0 + 4];
    const void* e0_bo= d_in[I_e0 + 5];
    const void* e1_g = d_in[I_e1 + 0];
    const void* e1_b = d_in[I_e1 + 1];
    const void* e1_wt= d_in[I_e1 + 2];
    const void* e1_bt= d_in[I_e1 + 3];
    const void* e1_wo= d_in[I_e1 + 4];
    const void* e1_bo= d_in[I_e1 + 5];
    const void* d0_g = d_in[I_d0 + 0];
    const void* d0_b = d_in[I_d0 + 1];
    const void* d0_wt= d_in[I_d0 + 2];
    const void* d0_bt= d_in[I_d0 + 3];
    const void* d0_wo= d_in[I_d0 + 4];
    const void* d0_bo= d_in[I_d0 + 5];
    const void* tg   = d_in[I_tg + 0];
    const void* tb   = d_in[I_tg + 1];
    const void* tpw  = d_in[I_tg + 2];
    const void* tpb  = d_in[I_tg + 3];
    const void* tdw  = d_in[I_tg + 4];
    const void* tdb  = d_in[I_tg + 5];
    const void* wsw  = d_in[I_ws + 0];
    const void* wb   = d_in[I_ws + 1];

    float* W = (float*)d_ws;
    float*  WF1    = W + 0;        // 200*128 max = 25600
    float*  BF1    = W + 25600;    // 128
    float*  WF2    = W + 25728;    // 128*64 = 8192
    float*  BF2    = W + 33920;    // 64
    int*    dflag  = (int*)(W + 33984);
    float2* P_HEAD = (float2*)(W + 34048);    // 200*256 f2
    float2* P_E0   = (float2*)(W + 136448);   // 128*256 f2
    float2* P_E1   = (float2*)(W + 201984);   // 64*1024 f2
    float2* P_D0a  = (float2*)(W + 333056);   // 32*256 f2
    float2* P_D0b  = (float2*)(W + 349440);   // 64*1024 f2
    float2* P_Ta   = (float2*)(W + 480512);   // 64*1024 f2
    float2* P_Tb   = (float2*)(W + 611584);   // 128*256 f2
    float*  R0     = W + 677120;              // 16384*128
    float*  R1     = R0 + (long)N0 * 128;     // 16384*128 (enc0)
    float*  T1     = R1 + (long)N0 * 128;     // 16384*128
    float*  H1b    = T1 + (long)N0 * 128;     // 4096*128
    float*  THb    = H1b + (long)N1 * 128;    // 4096*128
    float*  OUTb   = THb + (long)N1 * 128;    // 4096*64
    float*  ENC1   = OUTb + (long)N1 * 64;    // 4096*64
    float*  H2b    = ENC1 + (long)N1 * 64;    // 1024*64
    float*  HDb    = H2b + (long)N2 * 64;     // 1024*32
    float*  HDEC   = HDb + (long)N2 * 32;     // 4096*64

    // 1. head BN stage A (+ dtype detect, writes dflag)
    bnx_kernel<<<256, 256, 0, stream>>>(x, P_HEAD, dflag);
    // 2. head BN reduce + fold 1x1 conv
    bnfold_kernel<<<128, 256, 0, stream>>>(P_HEAD, 256, C_IN, P_HEAD, 256, N0,
                                           hg, hb, hpw, hpb, WF1, BF1, C_IN, 128, 1, dflag);
    // 3. head pointwise GEMM + leaky
    gemm4_dyn_kernel<<<2048, 256, 0, stream>>>(x, WF1, BF1, R0, C_IN, 128, dflag);
    // 4. head depthwise 5x5 -> enc0
    dw4_kernel<<<2048, 256, 0, stream>>>(R0, hdw, hdb, R1, dflag);
    // 5. pool4 + e0 BN stage A + tail-BN raw stats of enc0
    bnpool_kernel<<<256, 128, 0, stream>>>(R1, H1b, P_E0, P_Tb);
    // 6. e0 BN reduce + fold wt/wo
    bnfold2_kernel<<<192, 256, 0, stream>>>(P_E0, 256, 128, P_E0, 256, N1, e0_g, e0_b,
                                            e0_wt, e0_bt, e0_wo, e0_bo,
                                            WF1, BF1, WF2, BF2, 128, 128, 64, dflag);
    // 7. e0 theta+out GEMMs
    gemm2_f32_kernel<<<768, 256, 0, stream>>>(H1b, WF1, BF1, THb, 128, WF2, BF2, OUTb, 64, 128, 512);
    // 8. e0 attention -> ENC1, fused pool4 -> H2b, e1-stats, d0-stats(ch 32..95)
    attn_fused_kernel<0><<<1024, 256, 0, stream>>>(THb, OUTb, nbr_a, ENC1, 64, H2b, P_E1, P_D0b, 1024);
    // 9. e1 BN reduce + fold
    bnfold2_kernel<<<160, 256, 0, stream>>>(P_E1, 1024, 64, P_E1, 1024, N2, e1_g, e1_b,
                                            e1_wt, e1_bt, e1_wo, e1_bo,
                                            WF1, BF1, WF2, BF2, 64, 128, 32, dflag);
    // 10. e1 GEMMs
    gemm2_f32_kernel<<<160, 256, 0, stream>>>(H2b, WF1, BF1, THb, 128, WF2, BF2, OUTb, 32, 64, 128);
    // 11. e1 attention -> HDb + d0-stats(ch 0..31, x4 weight)
    attn_fused_kernel<1><<<256, 256, 0, stream>>>(THb, OUTb, nbr_b, HDb, 32, nullptr, nullptr, P_D0a, 256);
    // 12. d0 BN reduce + fold (mixed partials)
    bnfold2_kernel<<<192, 256, 0, stream>>>(P_D0a, 256, 32, P_D0b, 1024, N1, d0_g, d0_b,
                                            d0_wt, d0_bt, d0_wo, d0_bo,
                                            WF1, BF1, WF2, BF2, 96, 128, 64, dflag);
    // 13. d0 GEMMs on virtual concat [HDb | ENC1]
    gemm2cat_kernel<32><<<768, 256, 0, stream>>>(HDb, 32, ENC1, 64,
                                                 WF1, BF1, THb, 128, WF2, BF2, OUTb, 64, 96, 512);
    // 14. d0 attention -> HDEC + tail-stats(ch 0..63, x4 weight)
    attn_fused_kernel<2><<<1024, 256, 0, stream>>>(THb, OUTb, nbr_a, HDEC, 64, nullptr, nullptr, P_Ta, 1024);
    // 15. tail BN reduce + fold (mixed partials)
    bnfold_kernel<<<128, 256, 0, stream>>>(P_Ta, 1024, 64, P_Tb, 256, N0,
                                           tg, tb, tpw, tpb, WF1, BF1, 192, 128, 1, dflag);
    // 16. tail pointwise GEMM + leaky on virtual concat [HDEC | enc0]
    gemmcat_act_kernel<64><<<2048, 256, 0, stream>>>(HDEC, 64, R1, 128, WF1, BF1, T1, 192, 128);
    // 17. tail depthwise 5x5
    dw4_kernel<<<2048, 256, 0, stream>>>(T1, tdw, tdb, R0, dflag);
    // 18. classifier + softmax
    cls_kernel<<<1024, 256, 0, stream>>>(R0, wsw, wb, d_out, dflag);
}